// Round 6
// baseline (421.532 us; speedup 1.0000x reference)
//
#include <hip/hip_runtime.h>

// ---------------------------------------------------------------------------
// 12-qubit state-vector sim, one sample per 64-lane wave, 4 samples/block.
// Storage index p (12 bits): bits 0..5 = per-thread local index j,
// bits 6..11 = lane id. Logical index k = M*p over GF(2); CNOTs folded into
// M at compile time; each Rot gate = pair-mask (column of M^-1) + side-mask
// (row of M). Wire w <-> bit (11-w) of k (PennyLane big-endian).
// Invariant: parity(pair & side) == 1 (12-bit); partner's local side bit is
// sj ^ parity(pml & sml).
//
// Round-6 change: cross-lane exchanges moved from the DS pipe (ds_bpermute
// via __shfl_xor, ~3840 ops/wave, measured critical resource) to the VALU
// pipe: DPP quad_perm (xor1/2/3), row_half_mirror (xor7), row_mirror (xor15),
// and gfx950 v_permlane16/32_swap (xor16/32), composed for arbitrary lane-xor
// masks. No lgkmcnt waits, no DS contention; full-rate VALU.
// ---------------------------------------------------------------------------

#define N_GATES 48

typedef float v2f __attribute__((ext_vector_type(2)));

#if __has_builtin(__builtin_amdgcn_permlane16_swap) && __has_builtin(__builtin_amdgcn_permlane32_swap)
#define HAS_PLSWAP 1
#else
#define HAS_PLSWAP 0
#endif

struct Circ {
    unsigned pair[N_GATES];
    unsigned side[N_GATES];
    unsigned meas[12];
};

constexpr Circ make_circ() {
    Circ c{};
    unsigned Mrow[12] = {}, Ucol[12] = {};   // M rows, M^-1 columns
    for (int i = 0; i < 12; ++i) { Mrow[i] = 1u << i; Ucol[i] = 1u << i; }
    int g = 0;
    for (int l = 0; l < 4; ++l) {
        for (int w = 0; w < 12; ++w) {
            int b = 11 - w;
            c.pair[g] = Ucol[b];
            c.side[g] = Mrow[b];
            ++g;
        }
        // CNOT chain: (0,1),(1,2),...,(10,11) then (11,0); bits c=11-i, t=10-i
        for (int i = 0; i < 11; ++i) {
            int cb = 11 - i, tb = 10 - i;
            Mrow[tb] ^= Mrow[cb];
            Ucol[cb] ^= Ucol[tb];
        }
        Mrow[11] ^= Mrow[0];   // CNOT(11 -> 0): control bit 0, target bit 11
        Ucol[0]  ^= Ucol[11];
    }
    for (int w = 0; w < 12; ++w) c.meas[w] = Mrow[11 - w];
    return c;
}

constexpr Circ CIRC = make_circ();

// c-th pair slot for in-thread/mixed gates: insert a 0 bit at position MSB
__device__ __forceinline__ constexpr int pidx(int c, int msb) {
    return ((c & ~(msb - 1)) << 1) | (c & (msb - 1));
}

// ---- VALU-pipe lane-xor primitives --------------------------------------
// DPP quad_perm codes: xor1=[1,0,3,2]=0xB1, xor2=[2,3,0,1]=0x4E,
// xor3=[3,2,1,0]=0x1B; row_mirror=0x140 (xor15), row_half_mirror=0x141 (xor7)
__device__ __forceinline__ int dpp1(int w){ return __builtin_amdgcn_mov_dpp(w, 0xB1,  0xF, 0xF, true); }
__device__ __forceinline__ int dpp2(int w){ return __builtin_amdgcn_mov_dpp(w, 0x4E,  0xF, 0xF, true); }
__device__ __forceinline__ int dpp3(int w){ return __builtin_amdgcn_mov_dpp(w, 0x1B,  0xF, 0xF, true); }
__device__ __forceinline__ int dpp7(int w){ return __builtin_amdgcn_mov_dpp(w, 0x141, 0xF, 0xF, true); }
__device__ __forceinline__ int dppF(int w){ return __builtin_amdgcn_mov_dpp(w, 0x140, 0xF, 0xF, true); }

// lane-xor by V (0..15) within each 16-lane row, via DPP atom composition
template <unsigned V>
__device__ __forceinline__ int dpp_low(int w) {
    if constexpr (V == 0)  return w;
    else if constexpr (V == 1)  return dpp1(w);
    else if constexpr (V == 2)  return dpp2(w);
    else if constexpr (V == 3)  return dpp3(w);
    else if constexpr (V == 4)  return dpp3(dpp7(w));
    else if constexpr (V == 5)  return dpp2(dpp7(w));
    else if constexpr (V == 6)  return dpp1(dpp7(w));
    else if constexpr (V == 7)  return dpp7(w);
    else if constexpr (V == 8)  return dpp7(dppF(w));
    else if constexpr (V == 9)  return dpp1(dpp7(dppF(w)));
    else if constexpr (V == 10) return dpp2(dpp7(dppF(w)));
    else if constexpr (V == 11) return dpp3(dpp7(dppF(w)));
    else if constexpr (V == 12) return dpp3(dppF(w));
    else if constexpr (V == 13) return dpp2(dppF(w));
    else if constexpr (V == 14) return dpp1(dppF(w));
    else return dppF(w);   // V == 15
}

// full 6-bit lane-xor of one 32-bit word. l16 = lane&16, l32 = lane&32.
template <unsigned PMH>
__device__ __forceinline__ unsigned xword(unsigned w, bool l16, bool l32) {
    unsigned t = (unsigned)dpp_low<PMH & 15u>((int)w);
#if HAS_PLSWAP
    if constexpr ((PMH & 16u) != 0) {
        auto r = __builtin_amdgcn_permlane16_swap(t, t, false, false);
        // with equal inputs: r[0] rows = {x.r0,x.r0,x.r2,x.r2}, r[1] = {x.r1,x.r1,x.r3,x.r3}
        t = l16 ? r[0] : r[1];
    }
    if constexpr ((PMH & 32u) != 0) {
        auto r = __builtin_amdgcn_permlane32_swap(t, t, false, false);
        // r[0] = {x.lo,x.lo}, r[1] = {x.hi,x.hi}
        t = l32 ? r[0] : r[1];
    }
#else
    if constexpr ((PMH & 48u) != 0)
        t = (unsigned)__shfl_xor((int)t, (int)(PMH & 48u), 64);
#endif
    return t;
}

// partner value st[lane ^ PMH] for a packed complex element
template <unsigned PMH>
__device__ __forceinline__ v2f xpartner(v2f v, bool l16, bool l32) {
    union { v2f f; unsigned u[2]; } a;
    a.f = v;
    a.u[0] = xword<PMH>(a.u[0], l16, l32);
    a.u[1] = xword<PMH>(a.u[1], l16, l32);
    return a.f;
}

// acc + coef * X (complex), packed: coefR = {cr,cr}, coefN = {-ci,ci}
__device__ __forceinline__ v2f cmadd(v2f coefR, v2f coefN, v2f X, v2f acc) {
    acc = __builtin_elementwise_fma(coefR, X, acc);
    acc = __builtin_elementwise_fma(coefN, X.yx, acc);
    return acc;
}
__device__ __forceinline__ v2f cmul(v2f coefR, v2f coefN, v2f X) {
    return __builtin_elementwise_fma(coefR, X, coefN * X.yx);
}

template <int G>
__device__ __forceinline__ void apply_gate(v2f (&st)[64], const float* __restrict__ m,
                                           int lane, bool l16, bool l32) {
    constexpr unsigned pm  = CIRC.pair[G];
    constexpr unsigned sm  = CIRC.side[G];
    constexpr unsigned pml = pm & 63u;
    constexpr unsigned pmh = pm >> 6;
    constexpr unsigned sml = sm & 63u;
    constexpr unsigned smh = sm >> 6;
    constexpr bool flip = (__builtin_popcount(pml & sml) & 1) != 0;

    const float u00r = m[0], u00i = m[1], u01r = m[2], u01i = m[3];
    const float u10r = m[4], u10i = m[5], u11r = m[6], u11i = m[7];

    const int sL = __popc(lane & (int)smh) & 1;
    const float p0r = sL ? u11r : u00r, p0i = sL ? u11i : u00i;
    const float q0r = sL ? u10r : u01r, q0i = sL ? u10i : u01i;
    const float p1r = sL ? u00r : u11r, p1i = sL ? u00i : u11i;
    const float q1r = sL ? u01r : u10r, q1i = sL ? u01i : u10i;
    const v2f P0R = {p0r, p0r}, P0N = {-p0i, p0i};
    const v2f Q0R = {q0r, q0r}, Q0N = {-q0i, q0i};
    const v2f P1R = {p1r, p1r}, P1N = {-p1i, p1i};
    const v2f Q1R = {q1r, q1r}, Q1N = {-q1i, q1i};

    if constexpr (pmh == 0u) {
        // purely in-thread pairs
        constexpr int msb = 1 << (31 - __builtin_clz(pml));
#pragma unroll
        for (int c = 0; c < 32; ++c) {
            const int j  = pidx(c, msb);
            const int j2 = j ^ (int)pml;
            const bool sj  = __builtin_parity(j & (int)sml);
            const bool sjB = flip ? !sj : sj;
            const v2f A = st[j], B = st[j2];
            st[j]  = cmadd(sj  ? P1R : P0R, sj  ? P1N : P0N, A,
                     cmul (sj  ? Q1R : Q0R, sj  ? Q1N : Q0N, B));
            st[j2] = cmadd(sjB ? P1R : P0R, sjB ? P1N : P0N, B,
                     cmul (sjB ? Q1R : Q0R, sjB ? Q1N : Q0N, A));
        }
    } else if constexpr (pml == 0u) {
        // pure cross-lane: partner is same j in lane ^ pmh (VALU exchange)
#pragma unroll
        for (int j = 0; j < 64; ++j) {
            const v2f B = xpartner<pmh>(st[j], l16, l32);
            const bool sj = __builtin_parity(j & (int)sml);
            st[j] = cmadd(sj ? P1R : P0R, sj ? P1N : P0N, st[j],
                    cmul (sj ? Q1R : Q0R, sj ? Q1N : Q0N, B));
        }
    } else {
        // mixed: partner is (lane ^ pmh, j ^ pml) (VALU exchange)
        constexpr int msb = 1 << (31 - __builtin_clz(pml));
#pragma unroll
        for (int c = 0; c < 32; ++c) {
            const int j  = pidx(c, msb);
            const int j2 = j ^ (int)pml;
            const bool sj  = __builtin_parity(j & (int)sml);
            const bool sjB = flip ? !sj : sj;
            const v2f pa = xpartner<pmh>(st[j2], l16, l32);  // for output j
            const v2f pb = xpartner<pmh>(st[j],  l16, l32);  // for output j2
            const v2f A = st[j], B = st[j2];
            st[j]  = cmadd(sj  ? P1R : P0R, sj  ? P1N : P0N, A,
                     cmul (sj  ? Q1R : Q0R, sj  ? Q1N : Q0N, pa));
            st[j2] = cmadd(sjB ? P1R : P0R, sjB ? P1N : P0N, B,
                     cmul (sjB ? Q1R : Q0R, sjB ? Q1N : Q0N, pb));
        }
    }
}

template <int G>
__device__ __forceinline__ void apply_from(v2f (&st)[64], const float (*rotm)[8],
                                           int lane, bool l16, bool l32) {
    if constexpr (G < N_GATES) {
        apply_gate<G>(st, rotm[G], lane, l16, l32);
        apply_from<G + 1>(st, rotm, lane, l16, l32);
    }
}

__global__ __launch_bounds__(256, 2)
void qsim_kernel(const float* __restrict__ inputs,
                 const float* __restrict__ theta,
                 float* __restrict__ out, int B) {
    __shared__ float rotm[N_GATES][8];
    const int tid  = threadIdx.x;
    const int lane = tid & 63;
    const bool l16 = (lane & 16) != 0;
    const bool l32 = (lane & 32) != 0;
    int b = blockIdx.x * 4 + (tid >> 6);
    if (b >= B) b = B - 1;   // duplicate work, identical writes (B%4==0 normally)

    // ---- 48 shared Rot matrices (threads 0..47), PennyLane Rot(phi,th,om) ----
    if (tid < N_GATES) {
        const float* th = theta + tid * 3;   // tid = l*12 + w = gate index
        const float phi = th[0], tht = th[1], om = th[2];
        const float ct = __cosf(0.5f * tht), st = __sinf(0.5f * tht);
        const float a = 0.5f * (phi + om), d = 0.5f * (phi - om);
        const float ca = __cosf(a), sa = __sinf(a);
        const float cd = __cosf(d), sd = __sinf(d);
        rotm[tid][0] = ca * ct;  rotm[tid][1] = -sa * ct;   // u00 = e^{-ia} ct
        rotm[tid][2] = -cd * st; rotm[tid][3] = -sd * st;   // u01 = -e^{+id} st
        rotm[tid][4] = cd * st;  rotm[tid][5] = -sd * st;   // u10 = e^{-id} st
        rotm[tid][6] = ca * ct;  rotm[tid][7] = sa * ct;    // u11 = e^{+ia} ct
    }
    __syncthreads();

    // ---- init: RY-encoded product state (real) ----
    float cw[12], sw[12];
    const float* xin = inputs + b * 12;
#pragma unroll
    for (int w = 0; w < 12; ++w) {
        const float h = 0.5f * xin[w];
        cw[w] = __cosf(h);
        sw[w] = __sinf(h);
    }
    // lane bits: p bit (lb+6) <-> wire (5-lb)  =>  wire w (0..5) = lane bit (5-w)
    float prodL = 1.0f;
#pragma unroll
    for (int w = 0; w < 6; ++w)
        prodL *= ((lane >> (5 - w)) & 1) ? sw[w] : cw[w];

    float tmp[64];
    tmp[0] = prodL;
#pragma unroll
    for (int k = 0; k < 6; ++k) {            // local bit k <-> wire (11-k)
        const int n = 1 << k;
#pragma unroll
        for (int idx = 0; idx < n; ++idx) {
            const float v = tmp[idx];
            tmp[idx + n] = v * sw[11 - k];
            tmp[idx]     = v * cw[11 - k];
        }
    }
    v2f st[64];
#pragma unroll
    for (int j = 0; j < 64; ++j) st[j] = v2f{tmp[j], 0.0f};

    // ---- 4 layers x 12 Rot gates (CNOTs folded into masks) ----
    apply_from<0>(st, rotm, lane, l16, l32);

    // ---- measurement: <Z_q> = sum_p |amp|^2 * (1-2*parity(p & meas[q])) ----
    float sums[12];
#pragma unroll
    for (int q = 0; q < 12; ++q) sums[q] = 0.0f;
#pragma unroll
    for (int j = 0; j < 64; ++j) {
        const float p = st[j].x * st[j].x + st[j].y * st[j].y;
#pragma unroll
        for (int q = 0; q < 12; ++q) {
            if (__builtin_parity(j & (int)(CIRC.meas[q] & 63u)))
                sums[q] -= p;
            else
                sums[q] += p;
        }
    }
#pragma unroll
    for (int q = 0; q < 12; ++q) {
        float v = (__popc(lane & (int)(CIRC.meas[q] >> 6)) & 1) ? -sums[q] : sums[q];
        v += __shfl_xor(v, 32, 64);
        v += __shfl_xor(v, 16, 64);
        v += __shfl_xor(v, 8, 64);
        v += __shfl_xor(v, 4, 64);
        v += __shfl_xor(v, 2, 64);
        v += __shfl_xor(v, 1, 64);
        if (lane == 0) out[b * 12 + q] = v;
    }
}

extern "C" void kernel_launch(void* const* d_in, const int* in_sizes, int n_in,
                              void* d_out, int out_size, void* d_ws, size_t ws_size,
                              hipStream_t stream) {
    const float* inputs = (const float*)d_in[0];
    const float* theta  = (const float*)d_in[1];
    float* out = (float*)d_out;
    const int B = in_sizes[0] / 12;
    const int blocks = (B + 3) / 4;
    qsim_kernel<<<blocks, 256, 0, stream>>>(inputs, theta, out, B);
}

// Round 7
// 312.415 us; speedup vs baseline: 1.3493x; 1.3493x over previous
//
#include <hip/hip_runtime.h>

// ---------------------------------------------------------------------------
// 12-qubit state-vector sim, one sample per 64-lane wave, 4 samples/block.
// Storage index p (12 bits): bits 0..5 = per-thread local index j,
// bits 6..11 = lane id. Logical index k = M*p over GF(2); CNOTs folded into
// M at compile time; each Rot gate = pair-mask (column of M^-1) + side-mask
// (row of M). Wire w <-> bit (11-w) of k (PennyLane big-endian).
// Invariant: parity(pair & side) == 1 (12-bit); partner's local side bit is
// sj ^ parity(pml & sml).
//
// Round-7 change: HYBRID exchange-pipe assignment. R5 put all 3840 lane
// exchanges on the DS pipe (DS-bound, VALU 47%); R6 put all on VALU/DPP
// (VALU-bound, 90%, regressed: layer-2..4 masks cost 2-6 DPP atoms/word).
// Now each gate picks its pipe at compile time by DPP atom cost:
//   cost <= 2  -> DPP/permlane (2176 words, cheap masks: 1,2,3,4..8,12,15,16,32)
//   cost  > 2  -> ds_bpermute  (1664 words, expensive masks: 48,24,40,20,10,60,30,36)
// Both paths are verified end-to-end (R5/R6 passed with identical absmax).
// ---------------------------------------------------------------------------

#define N_GATES 48

typedef float v2f __attribute__((ext_vector_type(2)));

#if __has_builtin(__builtin_amdgcn_permlane16_swap) && __has_builtin(__builtin_amdgcn_permlane32_swap)
#define HAS_PLSWAP 1
#else
#define HAS_PLSWAP 0
#endif

struct Circ {
    unsigned pair[N_GATES];
    unsigned side[N_GATES];
    unsigned meas[12];
};

constexpr Circ make_circ() {
    Circ c{};
    unsigned Mrow[12] = {}, Ucol[12] = {};   // M rows, M^-1 columns
    for (int i = 0; i < 12; ++i) { Mrow[i] = 1u << i; Ucol[i] = 1u << i; }
    int g = 0;
    for (int l = 0; l < 4; ++l) {
        for (int w = 0; w < 12; ++w) {
            int b = 11 - w;
            c.pair[g] = Ucol[b];
            c.side[g] = Mrow[b];
            ++g;
        }
        // CNOT chain: (0,1),(1,2),...,(10,11) then (11,0); bits c=11-i, t=10-i
        for (int i = 0; i < 11; ++i) {
            int cb = 11 - i, tb = 10 - i;
            Mrow[tb] ^= Mrow[cb];
            Ucol[cb] ^= Ucol[tb];
        }
        Mrow[11] ^= Mrow[0];   // CNOT(11 -> 0): control bit 0, target bit 11
        Ucol[0]  ^= Ucol[11];
    }
    for (int w = 0; w < 12; ++w) c.meas[w] = Mrow[11 - w];
    return c;
}

constexpr Circ CIRC = make_circ();

// c-th pair slot for in-thread/mixed gates: insert a 0 bit at position MSB
__device__ __forceinline__ constexpr int pidx(int c, int msb) {
    return ((c & ~(msb - 1)) << 1) | (c & (msb - 1));
}

// DPP atom cost of a lane-xor mask (atoms: quad_perm / half_mirror / mirror
// compositions for the low nibble; permlane16/32_swap + select for bits 4,5)
constexpr int dpp_cost(unsigned pmh) {
    constexpr int low[16] = {0,1,1,1,2,2,2,1,2,3,3,3,2,2,2,1};
    int c = low[pmh & 15u];
    if (pmh & 16u) c += 2;
    if (pmh & 32u) c += 2;
    return c;
}

// ---- VALU-pipe lane-xor primitives --------------------------------------
__device__ __forceinline__ int dpp1(int w){ return __builtin_amdgcn_mov_dpp(w, 0xB1,  0xF, 0xF, true); }
__device__ __forceinline__ int dpp2(int w){ return __builtin_amdgcn_mov_dpp(w, 0x4E,  0xF, 0xF, true); }
__device__ __forceinline__ int dpp3(int w){ return __builtin_amdgcn_mov_dpp(w, 0x1B,  0xF, 0xF, true); }
__device__ __forceinline__ int dpp7(int w){ return __builtin_amdgcn_mov_dpp(w, 0x141, 0xF, 0xF, true); }
__device__ __forceinline__ int dppF(int w){ return __builtin_amdgcn_mov_dpp(w, 0x140, 0xF, 0xF, true); }

template <unsigned V>
__device__ __forceinline__ int dpp_low(int w) {
    if constexpr (V == 0)  return w;
    else if constexpr (V == 1)  return dpp1(w);
    else if constexpr (V == 2)  return dpp2(w);
    else if constexpr (V == 3)  return dpp3(w);
    else if constexpr (V == 4)  return dpp3(dpp7(w));
    else if constexpr (V == 5)  return dpp2(dpp7(w));
    else if constexpr (V == 6)  return dpp1(dpp7(w));
    else if constexpr (V == 7)  return dpp7(w);
    else if constexpr (V == 8)  return dpp7(dppF(w));
    else if constexpr (V == 9)  return dpp1(dpp7(dppF(w)));
    else if constexpr (V == 10) return dpp2(dpp7(dppF(w)));
    else if constexpr (V == 11) return dpp3(dpp7(dppF(w)));
    else if constexpr (V == 12) return dpp3(dppF(w));
    else if constexpr (V == 13) return dpp2(dppF(w));
    else if constexpr (V == 14) return dpp1(dppF(w));
    else return dppF(w);   // V == 15
}

template <unsigned PMH>
__device__ __forceinline__ unsigned xword(unsigned w, bool l16, bool l32) {
    unsigned t = (unsigned)dpp_low<PMH & 15u>((int)w);
#if HAS_PLSWAP
    if constexpr ((PMH & 16u) != 0) {
        auto r = __builtin_amdgcn_permlane16_swap(t, t, false, false);
        t = l16 ? r[0] : r[1];
    }
    if constexpr ((PMH & 32u) != 0) {
        auto r = __builtin_amdgcn_permlane32_swap(t, t, false, false);
        t = l32 ? r[0] : r[1];
    }
#else
    if constexpr ((PMH & 48u) != 0)
        t = (unsigned)__shfl_xor((int)t, (int)(PMH & 48u), 64);
#endif
    return t;
}

template <unsigned PMH>
__device__ __forceinline__ v2f xpartner(v2f v, bool l16, bool l32) {
    union { v2f f; unsigned u[2]; } a;
    a.f = v;
    a.u[0] = xword<PMH>(a.u[0], l16, l32);
    a.u[1] = xword<PMH>(a.u[1], l16, l32);
    return a.f;
}

// acc + coef * X (complex), packed: coefR = {cr,cr}, coefN = {-ci,ci}
__device__ __forceinline__ v2f cmadd(v2f coefR, v2f coefN, v2f X, v2f acc) {
    acc = __builtin_elementwise_fma(coefR, X, acc);
    acc = __builtin_elementwise_fma(coefN, X.yx, acc);
    return acc;
}
__device__ __forceinline__ v2f cmul(v2f coefR, v2f coefN, v2f X) {
    return __builtin_elementwise_fma(coefR, X, coefN * X.yx);
}

template <int G>
__device__ __forceinline__ void apply_gate(v2f (&st)[64], const float* __restrict__ m,
                                           int lane, bool l16, bool l32) {
    constexpr unsigned pm  = CIRC.pair[G];
    constexpr unsigned sm  = CIRC.side[G];
    constexpr unsigned pml = pm & 63u;
    constexpr unsigned pmh = pm >> 6;
    constexpr unsigned sml = sm & 63u;
    constexpr unsigned smh = sm >> 6;
    constexpr bool flip = (__builtin_popcount(pml & sml) & 1) != 0;
    constexpr bool use_dpp = (pmh != 0u) && (dpp_cost(pmh) <= 2);

    const float u00r = m[0], u00i = m[1], u01r = m[2], u01i = m[3];
    const float u10r = m[4], u10i = m[5], u11r = m[6], u11i = m[7];

    const int sL = __popc(lane & (int)smh) & 1;
    const float p0r = sL ? u11r : u00r, p0i = sL ? u11i : u00i;
    const float q0r = sL ? u10r : u01r, q0i = sL ? u10i : u01i;
    const float p1r = sL ? u00r : u11r, p1i = sL ? u00i : u11i;
    const float q1r = sL ? u01r : u10r, q1i = sL ? u01i : u10i;
    const v2f P0R = {p0r, p0r}, P0N = {-p0i, p0i};
    const v2f Q0R = {q0r, q0r}, Q0N = {-q0i, q0i};
    const v2f P1R = {p1r, p1r}, P1N = {-p1i, p1i};
    const v2f Q1R = {q1r, q1r}, Q1N = {-q1i, q1i};

    if constexpr (pmh == 0u) {
        // purely in-thread pairs
        constexpr int msb = 1 << (31 - __builtin_clz(pml));
#pragma unroll
        for (int c = 0; c < 32; ++c) {
            const int j  = pidx(c, msb);
            const int j2 = j ^ (int)pml;
            const bool sj  = __builtin_parity(j & (int)sml);
            const bool sjB = flip ? !sj : sj;
            const v2f A = st[j], B = st[j2];
            st[j]  = cmadd(sj  ? P1R : P0R, sj  ? P1N : P0N, A,
                     cmul (sj  ? Q1R : Q0R, sj  ? Q1N : Q0N, B));
            st[j2] = cmadd(sjB ? P1R : P0R, sjB ? P1N : P0N, B,
                     cmul (sjB ? Q1R : Q0R, sjB ? Q1N : Q0N, A));
        }
    } else if constexpr (pml == 0u) {
        // pure cross-lane: partner is same j in lane ^ pmh
        if constexpr (use_dpp) {
#pragma unroll
            for (int j = 0; j < 64; ++j) {
                const v2f B = xpartner<pmh>(st[j], l16, l32);
                const bool sj = __builtin_parity(j & (int)sml);
                st[j] = cmadd(sj ? P1R : P0R, sj ? P1N : P0N, st[j],
                        cmul (sj ? Q1R : Q0R, sj ? Q1N : Q0N, B));
            }
        } else {
            // DS path, batched 8 elements (16 bpermutes) per chunk
#pragma unroll
            for (int j0 = 0; j0 < 64; j0 += 8) {
                v2f Bv[8];
#pragma unroll
                for (int k = 0; k < 8; ++k) {
                    Bv[k].x = __shfl_xor(st[j0 + k].x, (int)pmh, 64);
                    Bv[k].y = __shfl_xor(st[j0 + k].y, (int)pmh, 64);
                }
#pragma unroll
                for (int k = 0; k < 8; ++k) {
                    const int j = j0 + k;
                    const bool sj = __builtin_parity(j & (int)sml);
                    st[j] = cmadd(sj ? P1R : P0R, sj ? P1N : P0N, st[j],
                            cmul (sj ? Q1R : Q0R, sj ? Q1N : Q0N, Bv[k]));
                }
            }
        }
    } else {
        // mixed: partner is (lane ^ pmh, j ^ pml)
        constexpr int msb = 1 << (31 - __builtin_clz(pml));
        if constexpr (use_dpp) {
#pragma unroll
            for (int c = 0; c < 32; ++c) {
                const int j  = pidx(c, msb);
                const int j2 = j ^ (int)pml;
                const bool sj  = __builtin_parity(j & (int)sml);
                const bool sjB = flip ? !sj : sj;
                const v2f pa = xpartner<pmh>(st[j2], l16, l32);  // for output j
                const v2f pb = xpartner<pmh>(st[j],  l16, l32);  // for output j2
                const v2f A = st[j], B = st[j2];
                st[j]  = cmadd(sj  ? P1R : P0R, sj  ? P1N : P0N, A,
                         cmul (sj  ? Q1R : Q0R, sj  ? Q1N : Q0N, pa));
                st[j2] = cmadd(sjB ? P1R : P0R, sjB ? P1N : P0N, B,
                         cmul (sjB ? Q1R : Q0R, sjB ? Q1N : Q0N, pb));
            }
        } else {
            // DS path, batched 4 pairs (16 bpermutes) per chunk
#pragma unroll
            for (int c0 = 0; c0 < 32; c0 += 4) {
                v2f tA[4], tB[4];
#pragma unroll
                for (int k = 0; k < 4; ++k) {
                    const int j  = pidx(c0 + k, msb);
                    const int j2 = j ^ (int)pml;
                    tA[k].x = __shfl_xor(st[j2].x, (int)pmh, 64);
                    tA[k].y = __shfl_xor(st[j2].y, (int)pmh, 64);
                    tB[k].x = __shfl_xor(st[j].x,  (int)pmh, 64);
                    tB[k].y = __shfl_xor(st[j].y,  (int)pmh, 64);
                }
#pragma unroll
                for (int k = 0; k < 4; ++k) {
                    const int j  = pidx(c0 + k, msb);
                    const int j2 = j ^ (int)pml;
                    const bool sj  = __builtin_parity(j & (int)sml);
                    const bool sjB = flip ? !sj : sj;
                    const v2f A = st[j], B = st[j2];
                    st[j]  = cmadd(sj  ? P1R : P0R, sj  ? P1N : P0N, A,
                             cmul (sj  ? Q1R : Q0R, sj  ? Q1N : Q0N, tA[k]));
                    st[j2] = cmadd(sjB ? P1R : P0R, sjB ? P1N : P0N, B,
                             cmul (sjB ? Q1R : Q0R, sjB ? Q1N : Q0N, tB[k]));
                }
            }
        }
    }
}

template <int G>
__device__ __forceinline__ void apply_from(v2f (&st)[64], const float (*rotm)[8],
                                           int lane, bool l16, bool l32) {
    if constexpr (G < N_GATES) {
        apply_gate<G>(st, rotm[G], lane, l16, l32);
        apply_from<G + 1>(st, rotm, lane, l16, l32);
    }
}

__global__ __launch_bounds__(256, 2)
void qsim_kernel(const float* __restrict__ inputs,
                 const float* __restrict__ theta,
                 float* __restrict__ out, int B) {
    __shared__ float rotm[N_GATES][8];
    const int tid  = threadIdx.x;
    const int lane = tid & 63;
    const bool l16 = (lane & 16) != 0;
    const bool l32 = (lane & 32) != 0;
    int b = blockIdx.x * 4 + (tid >> 6);
    if (b >= B) b = B - 1;   // duplicate work, identical writes (B%4==0 normally)

    // ---- 48 shared Rot matrices (threads 0..47), PennyLane Rot(phi,th,om) ----
    if (tid < N_GATES) {
        const float* th = theta + tid * 3;   // tid = l*12 + w = gate index
        const float phi = th[0], tht = th[1], om = th[2];
        const float ct = __cosf(0.5f * tht), st = __sinf(0.5f * tht);
        const float a = 0.5f * (phi + om), d = 0.5f * (phi - om);
        const float ca = __cosf(a), sa = __sinf(a);
        const float cd = __cosf(d), sd = __sinf(d);
        rotm[tid][0] = ca * ct;  rotm[tid][1] = -sa * ct;   // u00 = e^{-ia} ct
        rotm[tid][2] = -cd * st; rotm[tid][3] = -sd * st;   // u01 = -e^{+id} st
        rotm[tid][4] = cd * st;  rotm[tid][5] = -sd * st;   // u10 = e^{-id} st
        rotm[tid][6] = ca * ct;  rotm[tid][7] = sa * ct;    // u11 = e^{+ia} ct
    }
    __syncthreads();

    // ---- init: RY-encoded product state (real) ----
    float cw[12], sw[12];
    const float* xin = inputs + b * 12;
#pragma unroll
    for (int w = 0; w < 12; ++w) {
        const float h = 0.5f * xin[w];
        cw[w] = __cosf(h);
        sw[w] = __sinf(h);
    }
    // lane bits: p bit (lb+6) <-> wire (5-lb)  =>  wire w (0..5) = lane bit (5-w)
    float prodL = 1.0f;
#pragma unroll
    for (int w = 0; w < 6; ++w)
        prodL *= ((lane >> (5 - w)) & 1) ? sw[w] : cw[w];

    float tmp[64];
    tmp[0] = prodL;
#pragma unroll
    for (int k = 0; k < 6; ++k) {            // local bit k <-> wire (11-k)
        const int n = 1 << k;
#pragma unroll
        for (int idx = 0; idx < n; ++idx) {
            const float v = tmp[idx];
            tmp[idx + n] = v * sw[11 - k];
            tmp[idx]     = v * cw[11 - k];
        }
    }
    v2f st[64];
#pragma unroll
    for (int j = 0; j < 64; ++j) st[j] = v2f{tmp[j], 0.0f};

    // ---- 4 layers x 12 Rot gates (CNOTs folded into masks) ----
    apply_from<0>(st, rotm, lane, l16, l32);

    // ---- measurement: <Z_q> = sum_p |amp|^2 * (1-2*parity(p & meas[q])) ----
    float sums[12];
#pragma unroll
    for (int q = 0; q < 12; ++q) sums[q] = 0.0f;
#pragma unroll
    for (int j = 0; j < 64; ++j) {
        const float p = st[j].x * st[j].x + st[j].y * st[j].y;
#pragma unroll
        for (int q = 0; q < 12; ++q) {
            if (__builtin_parity(j & (int)(CIRC.meas[q] & 63u)))
                sums[q] -= p;
            else
                sums[q] += p;
        }
    }
#pragma unroll
    for (int q = 0; q < 12; ++q) {
        float v = (__popc(lane & (int)(CIRC.meas[q] >> 6)) & 1) ? -sums[q] : sums[q];
        v += __shfl_xor(v, 32, 64);
        v += __shfl_xor(v, 16, 64);
        v += __shfl_xor(v, 8, 64);
        v += __shfl_xor(v, 4, 64);
        v += __shfl_xor(v, 2, 64);
        v += __shfl_xor(v, 1, 64);
        if (lane == 0) out[b * 12 + q] = v;
    }
}

extern "C" void kernel_launch(void* const* d_in, const int* in_sizes, int n_in,
                              void* d_out, int out_size, void* d_ws, size_t ws_size,
                              hipStream_t stream) {
    const float* inputs = (const float*)d_in[0];
    const float* theta  = (const float*)d_in[1];
    float* out = (float*)d_out;
    const int B = in_sizes[0] / 12;
    const int blocks = (B + 3) / 4;
    qsim_kernel<<<blocks, 256, 0, stream>>>(inputs, theta, out, B);
}